// Round 1
// baseline (149.705 us; speedup 1.0000x reference)
//
#include <hip/hip_runtime.h>
#include <math.h>

// Problem constants (fixed by the reference: B=1, N=262144, D=64, C=10, T=4096)
constexpr int N_PIX   = 262144;
constexpr int C_CLS   = 10;
constexpr int D_FEAT  = 64;
constexpr int T_TRIP  = 4096;
constexpr float ALPHA = 1.0f, BETA = 1.0f, GAMMA = 1.0f;

constexpr int MSE_F4       = N_PIX * 3 / 4;        // 196608 float4 elements
constexpr int MSE_BLOCKS   = MSE_F4 / 256;         // 768
constexpr int CE_BLOCKS    = N_PIX / 256;          // 1024 (256 rows/block)
constexpr int TRIP_BLOCKS  = T_TRIP / 4;           // 1024 (4 waves/block, 1 triplet/wave)
constexpr int TOTAL_BLOCKS = MSE_BLOCKS + CE_BLOCKS + TRIP_BLOCKS;

__global__ __launch_bounds__(256) void loss_kernel(
    const float* __restrict__ gt_img,
    const float* __restrict__ gt_seg,
    const float* __restrict__ inr_out,
    const float* __restrict__ seg_out,
    const float* __restrict__ feat,
    const int*   __restrict__ aidx,
    const int*   __restrict__ pidx,
    const int*   __restrict__ nidx,
    float*       __restrict__ out)
{
    __shared__ float s_seg[256 * C_CLS];   // 10 KB
    __shared__ float s_gt [256 * C_CLS];   // 10 KB
    __shared__ float s_red[4];

    const int b   = blockIdx.x;
    const int tid = threadIdx.x;
    float local = 0.0f;

    if (b < MSE_BLOCKS) {
        // ---- MSE: one float4 per thread, fully coalesced ----
        const int i = b * 256 + tid;
        const float4 a = ((const float4*)inr_out)[i];
        const float4 g = ((const float4*)gt_img)[i];
        const float dx = a.x - g.x, dy = a.y - g.y, dz = a.z - g.z, dw = a.w - g.w;
        local = (dx*dx + dy*dy + dz*dz + dw*dw) * (ALPHA / (float)(N_PIX * 3));
    } else if (b < MSE_BLOCKS + CE_BLOCKS) {
        // ---- CE: 256 rows/block, LDS-staged coalesced loads ----
        const int row0 = (b - MSE_BLOCKS) * 256;
        const int base = row0 * C_CLS;
        #pragma unroll
        for (int k = 0; k < C_CLS; ++k) {
            s_seg[tid + k * 256] = seg_out[base + tid + k * 256];
            s_gt [tid + k * 256] = gt_seg [base + tid + k * 256];
        }
        __syncthreads();   // block-uniform branch: safe
        const float* x = &s_seg[tid * C_CLS];   // stride 10 -> 2-way bank alias (free)
        const float* g = &s_gt [tid * C_CLS];
        float m = x[0];
        #pragma unroll
        for (int c = 1; c < C_CLS; ++c) m = fmaxf(m, x[c]);
        float s = 0.f, dot = 0.f;
        #pragma unroll
        for (int c = 0; c < C_CLS; ++c) {
            s   += __expf(x[c] - m);
            dot += g[c] * x[c];
        }
        const float lse = m + __logf(s);
        // ce contribution: (lse - gt.x) summed over rows, * BETA/N
        local = (lse - dot) * (BETA / (float)N_PIX);
    } else {
        // ---- Triplet: one wave per triplet, lane = feature dim ----
        const int t    = (b - MSE_BLOCKS - CE_BLOCKS) * 4 + (tid >> 6);
        const int lane = tid & 63;
        const int ai = aidx[t], pi = pidx[t], ni = nidx[t];
        const float a = feat[ai * D_FEAT + lane];
        const float p = feat[pi * D_FEAT + lane];
        const float n = feat[ni * D_FEAT + lane];
        float dp = (a - p) * (a - p);
        float dn = (a - n) * (a - n);
        #pragma unroll
        for (int off = 32; off > 0; off >>= 1) {
            dp += __shfl_down(dp, off, 64);
            dn += __shfl_down(dn, off, 64);
        }
        if (lane == 0)
            local = fmaxf(sqrtf(dp) - sqrtf(dn), 0.0f) * GAMMA;
    }

    // ---- block reduce -> single atomicAdd per block ----
    #pragma unroll
    for (int off = 32; off > 0; off >>= 1)
        local += __shfl_down(local, off, 64);
    if ((tid & 63) == 0) s_red[tid >> 6] = local;
    __syncthreads();
    if (tid == 0)
        atomicAdd(out, s_red[0] + s_red[1] + s_red[2] + s_red[3]);
}

extern "C" void kernel_launch(void* const* d_in, const int* in_sizes, int n_in,
                              void* d_out, int out_size, void* d_ws, size_t ws_size,
                              hipStream_t stream) {
    const float* gt_img      = (const float*)d_in[0];
    const float* gt_seg      = (const float*)d_in[1];
    const float* inr_output  = (const float*)d_in[2];
    const float* seg_output  = (const float*)d_in[3];
    const float* inr_feats   = (const float*)d_in[4];
    const int*   anchor_idx  = (const int*)d_in[5];
    const int*   pos_idx     = (const int*)d_in[6];
    const int*   neg_idx     = (const int*)d_in[7];
    float* out = (float*)d_out;

    // d_out is re-poisoned (0xAA) before every timed launch -> zero it on-stream.
    hipMemsetAsync(out, 0, sizeof(float), stream);

    loss_kernel<<<TOTAL_BLOCKS, 256, 0, stream>>>(
        gt_img, gt_seg, inr_output, seg_output, inr_feats,
        anchor_idx, pos_idx, neg_idx, out);
}

// Round 2
// 123.510 us; speedup vs baseline: 1.2121x; 1.2121x over previous
//
#include <hip/hip_runtime.h>
#include <math.h>

// Problem constants (fixed by the reference: B=1, N=262144, D=64, C=10, T=4096)
constexpr int N_PIX   = 262144;
constexpr int C_CLS   = 10;
constexpr int D_FEAT  = 64;
constexpr int T_TRIP  = 4096;
constexpr float ALPHA = 1.0f, BETA = 1.0f, GAMMA = 1.0f;

constexpr int MSE_F4       = N_PIX * 3 / 4;        // 196608 float4 elements
constexpr int MSE_BLOCKS   = MSE_F4 / 256;         // 768
constexpr int CE_BLOCKS    = N_PIX / 256;          // 1024 (256 rows/block)
constexpr int TRIP_BLOCKS  = T_TRIP / 4;           // 1024 (4 waves/block, 1 triplet/wave)
constexpr int TOTAL_BLOCKS = MSE_BLOCKS + CE_BLOCKS + TRIP_BLOCKS;   // 2816

__global__ __launch_bounds__(256) void loss_kernel(
    const float* __restrict__ gt_img,
    const float* __restrict__ gt_seg,
    const float* __restrict__ inr_out,
    const float* __restrict__ seg_out,
    const float* __restrict__ feat,
    const int*   __restrict__ aidx,
    const int*   __restrict__ pidx,
    const int*   __restrict__ nidx,
    float*       __restrict__ partials)
{
    __shared__ float s_seg[256 * C_CLS];   // 10 KB
    __shared__ float s_gt [256 * C_CLS];   // 10 KB
    __shared__ float s_red[4];

    const int b   = blockIdx.x;
    const int tid = threadIdx.x;
    float local = 0.0f;

    if (b < MSE_BLOCKS) {
        // ---- MSE: one float4 per thread, fully coalesced ----
        const int i = b * 256 + tid;
        const float4 a = ((const float4*)inr_out)[i];
        const float4 g = ((const float4*)gt_img)[i];
        const float dx = a.x - g.x, dy = a.y - g.y, dz = a.z - g.z, dw = a.w - g.w;
        local = (dx*dx + dy*dy + dz*dz + dw*dw) * (ALPHA / (float)(N_PIX * 3));
    } else if (b < MSE_BLOCKS + CE_BLOCKS) {
        // ---- CE: 256 rows/block, float4 LDS staging (640 float4 per array) ----
        const int base4 = (b - MSE_BLOCKS) * (256 * C_CLS / 4);
        const float4* seg4 = (const float4*)seg_out;
        const float4* gt4  = (const float4*)gt_seg;
        #pragma unroll
        for (int i = tid; i < 256 * C_CLS / 4; i += 256) {
            ((float4*)s_seg)[i] = seg4[base4 + i];
            ((float4*)s_gt )[i] = gt4 [base4 + i];
        }
        __syncthreads();   // block-uniform branch: safe
        const float* x = &s_seg[tid * C_CLS];   // stride 10: 4-way bank alias (minor)
        const float* g = &s_gt [tid * C_CLS];
        float m = x[0];
        #pragma unroll
        for (int c = 1; c < C_CLS; ++c) m = fmaxf(m, x[c]);
        float s = 0.f, dot = 0.f;
        #pragma unroll
        for (int c = 0; c < C_CLS; ++c) {
            s   += __expf(x[c] - m);
            dot += g[c] * x[c];
        }
        const float lse = m + __logf(s);
        local = (lse - dot) * (BETA / (float)N_PIX);
    } else {
        // ---- Triplet: one wave per triplet, lane = feature dim ----
        const int t    = (b - MSE_BLOCKS - CE_BLOCKS) * 4 + (tid >> 6);
        const int lane = tid & 63;
        const int ai = aidx[t], pi = pidx[t], ni = nidx[t];
        const float a = feat[ai * D_FEAT + lane];
        const float p = feat[pi * D_FEAT + lane];
        const float n = feat[ni * D_FEAT + lane];
        float dp = (a - p) * (a - p);
        float dn = (a - n) * (a - n);
        #pragma unroll
        for (int off = 32; off > 0; off >>= 1) {
            dp += __shfl_down(dp, off, 64);
            dn += __shfl_down(dn, off, 64);
        }
        if (lane == 0)
            local = fmaxf(sqrtf(dp) - sqrtf(dn), 0.0f) * GAMMA;
    }

    // ---- block reduce -> ONE contention-free partial store per block ----
    #pragma unroll
    for (int off = 32; off > 0; off >>= 1)
        local += __shfl_down(local, off, 64);
    if ((tid & 63) == 0) s_red[tid >> 6] = local;
    __syncthreads();
    if (tid == 0)
        partials[b] = s_red[0] + s_red[1] + s_red[2] + s_red[3];
}

__global__ __launch_bounds__(256) void reduce_kernel(
    const float* __restrict__ partials, float* __restrict__ out)
{
    __shared__ float s_red[4];
    const int tid = threadIdx.x;
    float local = 0.0f;
    for (int i = tid; i < TOTAL_BLOCKS; i += 256)
        local += partials[i];
    #pragma unroll
    for (int off = 32; off > 0; off >>= 1)
        local += __shfl_down(local, off, 64);
    if ((tid & 63) == 0) s_red[tid >> 6] = local;
    __syncthreads();
    if (tid == 0)
        out[0] = s_red[0] + s_red[1] + s_red[2] + s_red[3];
}

extern "C" void kernel_launch(void* const* d_in, const int* in_sizes, int n_in,
                              void* d_out, int out_size, void* d_ws, size_t ws_size,
                              hipStream_t stream) {
    const float* gt_img      = (const float*)d_in[0];
    const float* gt_seg      = (const float*)d_in[1];
    const float* inr_output  = (const float*)d_in[2];
    const float* seg_output  = (const float*)d_in[3];
    const float* inr_feats   = (const float*)d_in[4];
    const int*   anchor_idx  = (const int*)d_in[5];
    const int*   pos_idx     = (const int*)d_in[6];
    const int*   neg_idx     = (const int*)d_in[7];
    float* out      = (float*)d_out;
    float* partials = (float*)d_ws;   // TOTAL_BLOCKS floats, fully rewritten each call

    loss_kernel<<<TOTAL_BLOCKS, 256, 0, stream>>>(
        gt_img, gt_seg, inr_output, seg_output, inr_feats,
        anchor_idx, pos_idx, neg_idx, partials);
    reduce_kernel<<<1, 256, 0, stream>>>(partials, out);
}